// Round 17
// baseline (366.689 us; speedup 1.0000x reference)
//
#include <hip/hip_runtime.h>
#include <math.h>

#define NN 16384
#define QPW 2
#define CAP 128   // per-wave LDS candidate buffer (u64 keys)
#define WM 64     // shrink watermark; push adds <=64, shrink keeps cnt<=127
#define KTOP 17   // keep top-17 (incl. self at dist~0), drop self at output
#define G 32      // grid cells per dim
#define GLO (-6.0f)
#define GW (12.0f / G)
#define GINVW (G / 12.0f)

typedef unsigned long long u64;

// ---------------- pack coords: x[:, :3] -> float4(x,y,z,|p|^2) ----------------
__global__ __launch_bounds__(256) void pack_coords(const float* __restrict__ x,
                                                   float4* __restrict__ coo) {
  int i = blockIdx.x * 256 + threadIdx.x;
  float a = x[i * 64 + 0];
  float b = x[i * 64 + 1];
  float c = x[i * 64 + 2];
  coo[i] = make_float4(a, b, c, a * a + b * b + c * c);
}

__device__ __forceinline__ int mbcnt64(u64 mask) {
  return __builtin_amdgcn_mbcnt_hi(
      (unsigned)(mask >> 32),
      __builtin_amdgcn_mbcnt_lo((unsigned)mask, 0));
}

// monotone float -> uint mapping (preserves total order incl. negatives)
__device__ __forceinline__ unsigned fmap(float d) {
  unsigned ub = __float_as_uint(d);
  return ub ^ ((unsigned)((int)ub >> 31) | 0x80000000u);
}

__device__ __forceinline__ float unfmap(unsigned ub) {
  unsigned fb = (ub & 0x80000000u) ? (ub ^ 0x80000000u) : ~ub;
  return __uint_as_float(fb);
}

// fp32 <-> bf16 (RNE, NaN-free data)
__device__ __forceinline__ unsigned short f2bf(float f) {
  unsigned u = __float_as_uint(f);
  return (unsigned short)((u + 0x7FFFu + ((u >> 16) & 1u)) >> 16);
}
__device__ __forceinline__ float bf2f(unsigned short h) {
  return __uint_as_float(((unsigned)h) << 16);
}

__device__ __forceinline__ u64 u64min(u64 a, u64 b) { return a < b ? a : b; }
__device__ __forceinline__ u64 u64max(u64 a, u64 b) { return a > b ? a : b; }

// full bitonic sort of 128 u64 keys held as 2 regs/lane (ascending)
__device__ __forceinline__ void sort128(u64& r0, u64& r1, int lane) {
#pragma unroll
  for (int k = 2; k <= 128; k <<= 1) {
    if (k == 128) {
      u64 lo = u64min(r0, r1);
      r1 = u64max(r0, r1);
      r0 = lo;
    }
#pragma unroll
    for (int jj = (k == 128 ? 32 : (k >> 1)); jj >= 1; jj >>= 1) {
      const bool up = (lane & jj) == 0;
      const bool asc0 = (lane & k) == 0;
      const bool asc1 = ((lane | 64) & k) == 0;
      u64 o0 = __shfl_xor(r0, jj);
      u64 o1 = __shfl_xor(r1, jj);
      r0 = (up == asc0) ? u64min(r0, o0) : u64max(r0, o0);
      r1 = (up == asc1) ? u64min(r1, o1) : u64max(r1, o1);
    }
  }
}

// radix-select shrink to exact top-KTOP (ties kept; compacts; tightens th)
__device__ __forceinline__ void radix_shrink(u64* buf, int& cnt, float& th,
                                             int lane) {
  const u64 k0 = (lane < cnt) ? buf[lane] : ~0ull;
  const u64 k1 = (lane + 64 < cnt) ? buf[lane + 64] : ~0ull;
  const unsigned d0 = (unsigned)(k0 >> 32);
  const unsigned d1 = (unsigned)(k1 >> 32);
  unsigned p = 0u;
#pragma unroll
  for (int b = 31; b >= 0; --b) {
    const unsigned c = p | (1u << b);
    const u64 b0 = __ballot(d0 < c);
    const u64 b1 = __ballot(d1 < c);
    const int n = __popcll(b0) + __popcll(b1);
    if (n < KTOP) p = c;
  }
  const bool v0 = d0 <= p;
  const bool v1 = d1 <= p;
  const u64 m0 = __ballot(v0);
  const u64 m1 = __ballot(v1);
  const int base = __popcll(m0);
  if (v0) buf[mbcnt64(m0)] = k0;
  if (v1) buf[base + mbcnt64(m1)] = k1;
  cnt = base + __popcll(m1);
  th = unfmap(p);
}

__device__ __forceinline__ int cell_of(float v) {
  int c = (int)floorf((v - GLO) * GINVW);
  return min(max(c, 0), G - 1);
}

// ---------------- grid build ----------------
__global__ __launch_bounds__(256) void grid_zero(int* __restrict__ counts) {
  counts[blockIdx.x * 256 + threadIdx.x] = 0;
}

__global__ __launch_bounds__(256) void grid_count(const float4* __restrict__ coo,
                                                  int* __restrict__ counts) {
  const int i = blockIdx.x * 256 + threadIdx.x;
  const float4 p = coo[i];
  const int cell = (cell_of(p.z) * G + cell_of(p.y)) * G + cell_of(p.x);
  atomicAdd(&counts[cell], 1);
}

// single-block exclusive scan over G^3 counts -> cellStart (+total), cursor
__global__ __launch_bounds__(1024) void grid_scan(const int* __restrict__ counts,
                                                  int* __restrict__ cellStart,
                                                  int* __restrict__ cursor) {
  __shared__ int part[1024];
  const int t = threadIdx.x;
  const int base = t * (G * G * G / 1024);
  int sum = 0;
  for (int i = 0; i < G * G * G / 1024; ++i) sum += counts[base + i];
  part[t] = sum;
  __syncthreads();
  for (int off = 1; off < 1024; off <<= 1) {
    int v = (t >= off) ? part[t - off] : 0;
    __syncthreads();
    part[t] += v;
    __syncthreads();
  }
  int run = (t == 0) ? 0 : part[t - 1];
  for (int i = 0; i < G * G * G / 1024; ++i) {
    const int c = counts[base + i];
    cellStart[base + i] = run;
    cursor[base + i] = run;
    run += c;
  }
  if (t == 1023) cellStart[G * G * G] = run;
}

__global__ __launch_bounds__(256) void grid_scatter(
    const float4* __restrict__ coo, int* __restrict__ cursor,
    float4* __restrict__ scoo, int* __restrict__ sidx) {
  const int i = blockIdx.x * 256 + threadIdx.x;
  const float4 p = coo[i];
  const int cell = (cell_of(p.z) * G + cell_of(p.y)) * G + cell_of(p.x);
  const int pos = atomicAdd(&cursor[cell], 1);
  scoo[pos] = p;
  sidx[pos] = i;
}

// ---------------- kNN via spatial grid: one wave per query. -----------------
// Process 3x3x3 cell block (contiguous x-runs), expand Chebyshev rings until
// exact 17th-best <= squared distance to processed-block boundary. Same
// distance formula / keys / select machinery as the proven brute kernel ->
// identical selected sets. Scatter order irrelevant (selection is set-based).
__global__ __launch_bounds__(256) void knn_grid(
    const float4* __restrict__ scoo, const int* __restrict__ sidx,
    const int* __restrict__ cellStart, const float4* __restrict__ coo,
    int* __restrict__ src) {
  __shared__ u64 bufs[4][CAP];  // 4 KB
  const int lane = threadIdx.x & 63;
  const int wid = threadIdx.x >> 6;
  const int node = blockIdx.x * 4 + wid;
  u64* buf = bufs[wid];

  const float4 me = coo[node];
  const float nx = -2.0f * me.x, ny = -2.0f * me.y, nz = -2.0f * me.z;
  const float sq = me.w;
  const int hx = cell_of(me.x), hy = cell_of(me.y), hz = cell_of(me.z);

  float th = __builtin_inff();
  int cnt = 0;

  auto runrange = [&](int x0, int x1, int y, int z) {
    const int b = (z * G + y) * G;
    const int rs = cellStart[b + x0];
    const int re = cellStart[b + x1 + 1];
    for (int bs = rs; bs < re; bs += 64) {
      const int i = bs + lane;
      const int ic = min(i, NN - 1);
      const float4 p = scoo[ic];
      const int id = sidx[ic];
      float acc = fmaf(nz, p.z, p.w);
      acc = fmaf(ny, p.y, acc);
      acc = fmaf(nx, p.x, acc);
      const float d = sq + acc;
      const bool val = (i < re) && (d <= th);
      const u64 mk = __ballot(val);
      if (mk) {
        if (val)
          buf[cnt + mbcnt64(mk)] = ((u64)fmap(d) << 32) | (unsigned)id;
        cnt += __popcll(mk);
        if (cnt >= WM) radix_shrink(buf, cnt, th, lane);
      }
    }
  };

  // block s=1: 9 contiguous x-runs
  for (int dz = -1; dz <= 1; ++dz) {
    const int z = hz + dz;
    if (z < 0 || z >= G) continue;
    for (int dy = -1; dy <= 1; ++dy) {
      const int y = hy + dy;
      if (y < 0 || y >= G) continue;
      runrange(max(hx - 1, 0), min(hx + 1, G - 1), y, z);
    }
  }

  int s = 1;
  while (true) {
    if (cnt >= KTOP) {
      radix_shrink(buf, cnt, th, lane);  // exact 17th -> th
      float dmin = 1e30f;
      if (hx - s > 0) dmin = fminf(dmin, me.x - (GLO + (hx - s) * GW));
      if (hx + s < G - 1) dmin = fminf(dmin, (GLO + (hx + s + 1) * GW) - me.x);
      if (hy - s > 0) dmin = fminf(dmin, me.y - (GLO + (hy - s) * GW));
      if (hy + s < G - 1) dmin = fminf(dmin, (GLO + (hy + s + 1) * GW) - me.y);
      if (hz - s > 0) dmin = fminf(dmin, me.z - (GLO + (hz - s) * GW));
      if (hz + s < G - 1) dmin = fminf(dmin, (GLO + (hz + s + 1) * GW) - me.z);
      dmin = fmaxf(dmin, 0.0f);
      if (th <= dmin * dmin * 0.9999f) break;
    }
    ++s;
    if (s > G) break;  // whole grid processed
    for (int dz = -s; dz <= s; ++dz) {
      const int z = hz + dz;
      if (z < 0 || z >= G) continue;
      for (int dy = -s; dy <= s; ++dy) {
        const int y = hy + dy;
        if (y < 0 || y >= G) continue;
        if (dz == -s || dz == s || dy == -s || dy == s) {
          runrange(max(hx - s, 0), min(hx + s, G - 1), y, z);
        } else {
          if (hx - s >= 0) runrange(hx - s, hx - s, y, z);
          if (hx + s <= G - 1) runrange(hx + s, hx + s, y, z);
        }
      }
    }
  }

  // final: exact (d, idx)-sorted top-17, drop self, write 16
  u64 r0 = (lane < cnt) ? buf[lane] : ~0ull;
  u64 r1 = (lane + 64 < cnt) ? buf[lane + 64] : ~0ull;
  sort128(r0, r1, lane);
  const int idx = (int)(r0 & 0xFFFFFFFFull);
  const u64 selfm = __ballot((lane < KTOP) && (idx == node));
  const int sf = selfm ? (__ffsll((long long)selfm) - 1) : 99;
  const int outrank = lane - (lane > sf ? 1 : 0);
  if (lane < KTOP && lane != sf && outrank < 16) src[node * 16 + outrank] = idx;
}

// ---------------- fused q|k|v|s GEMM: [N,KD] x 4x[KD,128] ----------
template <int KD>
__global__ __launch_bounds__(256) void gemm_qkvs(
    const float* __restrict__ X, const float* __restrict__ W0,
    const float* __restrict__ W1, const float* __restrict__ W2,
    const float* __restrict__ W3, const float* __restrict__ B0,
    const float* __restrict__ B1, const float* __restrict__ B2,
    const float* __restrict__ B3, float* __restrict__ qs,
    unsigned short* __restrict__ kvh) {
  __shared__ float As[64][68];
  __shared__ float Bs[64][64];
  const int brow = blockIdx.x * 64;
  const int by = blockIdx.y;
  const int wi = by >> 1;
  const float* W = wi == 0 ? W0 : wi == 1 ? W1 : wi == 2 ? W2 : W3;
  const float* bias = wi == 0 ? B0 : wi == 1 ? B1 : wi == 2 ? B2 : B3;
  const int cbase = (by & 1) * 64;
  const int tx = threadIdx.x & 15;
  const int ty = threadIdx.x >> 4;

  float acc[4][4] = {};
  for (int k0 = 0; k0 < KD; k0 += 64) {
    __syncthreads();
#pragma unroll
    for (int i = 0; i < 4; ++i) {
      const int flat = threadIdx.x * 4 + i * 1024;
      const int r = flat >> 6, kk = flat & 63;
      const float4 v = *(const float4*)&X[(brow + r) * KD + k0 + kk];
      As[kk + 0][r] = v.x;
      As[kk + 1][r] = v.y;
      As[kk + 2][r] = v.z;
      As[kk + 3][r] = v.w;
    }
#pragma unroll
    for (int i = 0; i < 4; ++i) {
      const int flat = threadIdx.x * 4 + i * 1024;
      const int kk = flat >> 6, c = flat & 63;
      *(float4*)&Bs[kk][c] = *(const float4*)&W[(k0 + kk) * 128 + cbase + c];
    }
    __syncthreads();
#pragma unroll 8
    for (int k = 0; k < 64; ++k) {
      const float4 a = *(const float4*)&As[k][ty * 4];
      const float4 b = *(const float4*)&Bs[k][tx * 4];
      const float av[4] = {a.x, a.y, a.z, a.w};
      const float bv[4] = {b.x, b.y, b.z, b.w};
#pragma unroll
      for (int i = 0; i < 4; ++i)
#pragma unroll
        for (int jj = 0; jj < 4; ++jj)
          acc[i][jj] = fmaf(av[i], bv[jj], acc[i][jj]);
    }
  }
  const float4 bi = *(const float4*)&bias[cbase + tx * 4];
  const int col = cbase + tx * 4;
#pragma unroll
  for (int i = 0; i < 4; ++i) {
    const int row = brow + ty * 4 + i;
    float4 o;
    o.x = acc[i][0] + bi.x;
    o.y = acc[i][1] + bi.y;
    o.z = acc[i][2] + bi.z;
    o.w = acc[i][3] + bi.w;
    if (wi == 0) {
      *(float4*)&qs[row * 256 + col] = o;
    } else if (wi == 3) {
      *(float4*)&qs[row * 256 + 128 + col] = o;
    } else {
      ushort4 h;
      h.x = f2bf(o.x);
      h.y = f2bf(o.y);
      h.z = f2bf(o.z);
      h.w = f2bf(o.w);
      *(ushort4*)&kvh[row * 256 + (wi == 1 ? col : 128 + col)] = h;
    }
  }
}

// ---------------- attention, c=128: 32-lane group per node ----
__global__ __launch_bounds__(256) void attn_c128(
    const float* __restrict__ qs, const unsigned short* __restrict__ kvh,
    const int* __restrict__ src, const float* __restrict__ res,
    float* __restrict__ hout, int do_res) {
  const int g = threadIdx.x >> 5;
  const int node = blockIdx.x * 8 + g;
  const int c = threadIdx.x & 31;
  const float4 q4 = ((const float4*)(qs + node * 256))[c];

  int nb[16];
#pragma unroll
  for (int r = 0; r < 16; ++r) nb[r] = src[node * 16 + r];

  float p[16];
#pragma unroll
  for (int r = 0; r < 16; ++r) {
    const ushort4 k4 = ((const ushort4*)(kvh + nb[r] * 256))[c];
    p[r] = q4.x * bf2f(k4.x) + q4.y * bf2f(k4.y) + q4.z * bf2f(k4.z) +
           q4.w * bf2f(k4.w);
  }
#pragma unroll
  for (int o = 16; o; o >>= 1) {
#pragma unroll
    for (int r = 0; r < 16; ++r) p[r] += __shfl_xor(p[r], o);
  }

  float m = p[0];
#pragma unroll
  for (int r = 1; r < 16; ++r) m = fmaxf(m, p[r]);
  float w[16];
  float den = 0.0f;
#pragma unroll
  for (int r = 0; r < 16; ++r) {
    w[r] = __expf((p[r] - m) * 0.088388347648318447f);
    den += w[r];
  }
  const float inv = 1.0f / den;
  float o0 = 0.0f, o1 = 0.0f, o2 = 0.0f, o3 = 0.0f;
#pragma unroll
  for (int r = 0; r < 16; ++r) {
    const ushort4 v4 = ((const ushort4*)(kvh + nb[r] * 256 + 128))[c];
    const float ww = w[r] * inv;
    o0 = fmaf(ww, bf2f(v4.x), o0);
    o1 = fmaf(ww, bf2f(v4.y), o1);
    o2 = fmaf(ww, bf2f(v4.z), o2);
    o3 = fmaf(ww, bf2f(v4.w), o3);
  }
  const float4 s4 = ((const float4*)(qs + node * 256 + 128))[c];
  float r0 = o0 + s4.x, r1 = o1 + s4.y, r2 = o2 + s4.z, r3 = o3 + s4.w;
  if (do_res) {
    const float4 h4 = ((const float4*)(res + node * 128))[c];
    r0 += h4.x;
    r1 += h4.y;
    r2 += h4.z;
    r3 += h4.w;
  }
  ((float4*)(hout + node * 128))[c] =
      make_float4(tanhf(r0), tanhf(r1), tanhf(r2), tanhf(r3));
}

// ---------------- layer 3 GEMM: [N,128] x 4x[128,3] -> [N,12] ----------------
__global__ __launch_bounds__(256) void gemm_qkvs3(
    const float* __restrict__ H, const float* __restrict__ W0,
    const float* __restrict__ W1, const float* __restrict__ W2,
    const float* __restrict__ W3, const float* __restrict__ B0,
    const float* __restrict__ B1, const float* __restrict__ B2,
    const float* __restrict__ B3, float* __restrict__ out) {
  __shared__ float hs[64][132];
  __shared__ float wsh[128 * 12];
  __shared__ float bsh[12];
  const int brow = blockIdx.x * 64;
  if (threadIdx.x < 12) {
    const int mi = threadIdx.x / 3, c = threadIdx.x % 3;
    const float* Bsel = mi == 0 ? B0 : mi == 1 ? B1 : mi == 2 ? B2 : B3;
    bsh[threadIdx.x] = Bsel[c];
  }
  for (int t = threadIdx.x; t < 1536; t += 256) {
    const int k = t / 12, cc = t % 12;
    const int mi = cc / 3, c = cc % 3;
    const float* Wsel = mi == 0 ? W0 : mi == 1 ? W1 : mi == 2 ? W2 : W3;
    wsh[t] = Wsel[k * 3 + c];
  }
#pragma unroll
  for (int i = 0; i < 8; ++i) {
    const int flat = threadIdx.x * 4 + i * 1024;
    const int r = flat >> 7, kk = flat & 127;
    *(float4*)&hs[r][kk] = *(const float4*)&H[(brow + r) * 128 + kk];
  }
  __syncthreads();
  const int r = threadIdx.x >> 2;
  const int part = threadIdx.x & 3;
  float a0 = 0.0f, a1 = 0.0f, a2 = 0.0f;
#pragma unroll 4
  for (int k = 0; k < 128; ++k) {
    const float h = hs[r][k];
    a0 = fmaf(h, wsh[k * 12 + part * 3 + 0], a0);
    a1 = fmaf(h, wsh[k * 12 + part * 3 + 1], a1);
    a2 = fmaf(h, wsh[k * 12 + part * 3 + 2], a2);
  }
  const int row = brow + r;
  out[row * 12 + part * 3 + 0] = a0 + bsh[part * 3 + 0];
  out[row * 12 + part * 3 + 1] = a1 + bsh[part * 3 + 1];
  out[row * 12 + part * 3 + 2] = a2 + bsh[part * 3 + 2];
}

// ---------------- attention, c=3: 16 lanes per node ----------------
__global__ __launch_bounds__(256) void attn_c3(const float* __restrict__ q3,
                                               const int* __restrict__ src,
                                               float* __restrict__ out) {
  const int gid = blockIdx.x * 256 + threadIdx.x;
  const int node = gid >> 4, r = gid & 15;
  const int j = src[node * 16 + r];
  const float* qn = q3 + node * 12;
  const float* kj = q3 + j * 12 + 3;
  float alpha = (qn[0] * kj[0] + qn[1] * kj[1] + qn[2] * kj[2]) *
                0.57735026918962576f;
  float m = alpha;
#pragma unroll
  for (int o = 8; o; o >>= 1) m = fmaxf(m, __shfl_xor(m, o, 16));
  const float e = __expf(alpha - m);
  float den = e;
#pragma unroll
  for (int o = 8; o; o >>= 1) den += __shfl_xor(den, o, 16);
  const float wgt = e / den;
  const float* vj = q3 + j * 12 + 6;
  float o0 = wgt * vj[0], o1 = wgt * vj[1], o2 = wgt * vj[2];
#pragma unroll
  for (int o = 8; o; o >>= 1) {
    o0 += __shfl_xor(o0, o, 16);
    o1 += __shfl_xor(o1, o, 16);
    o2 += __shfl_xor(o2, o, 16);
  }
  if (r == 0) {
    const float* sn = q3 + node * 12 + 9;
    out[node * 3 + 0] = o0 + sn[0];
    out[node * 3 + 1] = o1 + sn[1];
    out[node * 3 + 2] = o2 + sn[2];
  }
}

extern "C" void kernel_launch(void* const* d_in, const int* in_sizes, int n_in,
                              void* d_out, int out_size, void* d_ws,
                              size_t ws_size, hipStream_t stream) {
  const float* x = (const float*)d_in[1];
  const float* Wq1 = (const float*)d_in[2];
  const float* bq1 = (const float*)d_in[3];
  const float* Wk1 = (const float*)d_in[4];
  const float* bk1 = (const float*)d_in[5];
  const float* Wv1 = (const float*)d_in[6];
  const float* bv1 = (const float*)d_in[7];
  const float* Ws1 = (const float*)d_in[8];
  const float* bs1 = (const float*)d_in[9];
  const float* Wq2 = (const float*)d_in[10];
  const float* bq2 = (const float*)d_in[11];
  const float* Wk2 = (const float*)d_in[12];
  const float* bk2 = (const float*)d_in[13];
  const float* Wv2 = (const float*)d_in[14];
  const float* bv2 = (const float*)d_in[15];
  const float* Ws2 = (const float*)d_in[16];
  const float* bs2 = (const float*)d_in[17];
  const float* Wq3 = (const float*)d_in[18];
  const float* bq3 = (const float*)d_in[19];
  const float* Wk3 = (const float*)d_in[20];
  const float* bk3 = (const float*)d_in[21];
  const float* Wv3 = (const float*)d_in[22];
  const float* bv3 = (const float*)d_in[23];
  const float* Ws3 = (const float*)d_in[24];
  const float* bs3 = (const float*)d_in[25];

  const size_t MB = 1024 * 1024;
  char* ws = (char*)d_ws;
  float* qs = (float*)(ws);                               // 16 MB (q|s fp32)
  unsigned short* kvh = (unsigned short*)(ws + 16 * MB);  // 8 MB (k|v bf16)
  float* h1 = (float*)(ws + 24 * MB);                     // 8 MB
  float* h2 = (float*)(ws + 32 * MB);                     // 8 MB
  int* src = (int*)(ws + 40 * MB);                        // 1 MB
  float4* coo = (float4*)(ws + 41 * MB);                  // 256 KB
  float* q3 = (float*)(ws + 42 * MB);                     // 768 KB
  int* counts = (int*)(ws + 43 * MB);                     // 128 KB
  int* cursor = (int*)(ws + 43 * MB + 128 * 1024);        // 128 KB
  int* cellStart = (int*)(ws + 43 * MB + 256 * 1024);     // 128 KB + 4
  float4* scoo = (float4*)(ws + 44 * MB);                 // 256 KB
  int* sidx = (int*)(ws + 44 * MB + 256 * 1024);          // 64 KB
  float* out = (float*)d_out;

  pack_coords<<<NN / 256, 256, 0, stream>>>(x, coo);
  grid_zero<<<G * G * G / 256, 256, 0, stream>>>(counts);
  grid_count<<<NN / 256, 256, 0, stream>>>(coo, counts);
  grid_scan<<<1, 1024, 0, stream>>>(counts, cellStart, cursor);
  grid_scatter<<<NN / 256, 256, 0, stream>>>(coo, cursor, scoo, sidx);
  knn_grid<<<NN / 4, 256, 0, stream>>>(scoo, sidx, cellStart, coo, src);
  gemm_qkvs<64><<<dim3(NN / 64, 8), 256, 0, stream>>>(
      x, Wq1, Wk1, Wv1, Ws1, bq1, bk1, bv1, bs1, qs, kvh);
  attn_c128<<<NN / 8, 256, 0, stream>>>(qs, kvh, src, nullptr, h1, 0);
  gemm_qkvs<128><<<dim3(NN / 64, 8), 256, 0, stream>>>(
      h1, Wq2, Wk2, Wv2, Ws2, bq2, bk2, bv2, bs2, qs, kvh);
  attn_c128<<<NN / 8, 256, 0, stream>>>(qs, kvh, src, h1, h2, 1);
  gemm_qkvs3<<<NN / 64, 256, 0, stream>>>(h2, Wq3, Wk3, Wv3, Ws3, bq3, bk3,
                                          bv3, bs3, q3);
  attn_c3<<<NN * 16 / 256, 256, 0, stream>>>(q3, src, out);
}